// Round 1
// baseline (716.391 us; speedup 1.0000x reference)
//
#include <hip/hip_runtime.h>
#include <math.h>

// Problem constants
#define N_ROWS 8192
#define M_COLS 2048
#define K_DIM  1024
#define NM     ((size_t)N_ROWS * M_COLS)

static __device__ __forceinline__ float dEPS()    { return 0.1f; }
#define INV_EPS   10.0f
#define LAM_EPS   (0.1f/1.1f)                 // (GAMMA/(GAMMA+EPS))*EPS
#define LOGA      (-9.010913347279288f)       // -log(8192)
#define LOG_M     (7.624618986159398f)        // log(2048)

// ---------------------------------------------------------------------------
// params: rho + logb from device scalars
// ---------------------------------------------------------------------------
__global__ void k_params(const int* __restrict__ iters, const int* __restrict__ ipe,
                         float* __restrict__ params)
{
    if (threadIdx.x == 0) {
        float ramp = 10.0f * (float)ipe[0];
        float rho;
        if (ramp == 0.0f) {
            rho = 1.0f + 0.1f;
        } else {
            float cur = fminf(fmaxf((float)iters[0], 0.0f), ramp);
            float phase = 1.0f - cur / ramp;
            rho = expf(-5.0f * phase * phase) * 1.0f + 0.1f;
        }
        rho = fminf(rho, 1.0f);
        params[0] = rho;
        params[1] = logf(rho) - LOG_M;   // logb
    }
}

// ---------------------------------------------------------------------------
// per-row stats: min, sum, and normalized sumsq  (cols == 1024, 256 thr/blk)
// ---------------------------------------------------------------------------
__global__ __launch_bounds__(256) void rowstats(
    const float* __restrict__ A, float* __restrict__ mn,
    float* __restrict__ sm, float* __restrict__ s2n)
{
    const int row = blockIdx.x, tid = threadIdx.x;
    const float4 v = ((const float4*)(A + (size_t)row * K_DIM))[tid];
    float lmin = fminf(fminf(v.x, v.y), fminf(v.z, v.w));
    float lsum = v.x + v.y + v.z + v.w;
    float lsq  = v.x*v.x + v.y*v.y + v.z*v.z + v.w*v.w;

    __shared__ float rmin[256], rsum[256], rsq[256];
    rmin[tid] = lmin; rsum[tid] = lsum; rsq[tid] = lsq;
    __syncthreads();
    for (int s = 128; s > 0; s >>= 1) {
        if (tid < s) {
            rmin[tid] = fminf(rmin[tid], rmin[tid + s]);
            rsum[tid] += rsum[tid + s];
            rsq[tid]  += rsq[tid + s];
        }
        __syncthreads();
    }
    if (tid == 0) {
        float m = rmin[0], s = rsum[0], q = rsq[0];
        mn[row]  = m;
        sm[row]  = s;
        s2n[row] = q - 2.0f * m * s + (float)K_DIM * m * m;  // ||a - m||^2
    }
}

// ---------------------------------------------------------------------------
// GEMM + cost epilogue: cost[i][j] = sqrt(max(d2,0)); track max(d2)
// 128x128 tile, 256 threads, 8x8 per thread, K-tile 16
// ---------------------------------------------------------------------------
__global__ __launch_bounds__(256) void gemm_cost(
    const float* __restrict__ X, const float* __restrict__ Y,
    const float* __restrict__ mx, const float* __restrict__ sx, const float* __restrict__ x2,
    const float* __restrict__ my, const float* __restrict__ sy, const float* __restrict__ y2,
    float* __restrict__ cost, unsigned int* __restrict__ d2max)
{
    __shared__ float As[16][132];
    __shared__ float Bs[16][132];
    const int tid = threadIdx.x;
    const int tx = tid & 15, ty = tid >> 4;
    const int i0 = blockIdx.y * 128, j0 = blockIdx.x * 128;

    float acc[8][8];
    #pragma unroll
    for (int u = 0; u < 8; ++u)
        #pragma unroll
        for (int v = 0; v < 8; ++v) acc[u][v] = 0.0f;

    for (int kt = 0; kt < K_DIM; kt += 16) {
        #pragma unroll
        for (int rep = 0; rep < 2; ++rep) {
            int id = tid + rep * 256;          // 0..511
            int r  = id >> 2;                  // 0..127
            int kq = (id & 3) << 2;            // 0,4,8,12
            float4 a = *(const float4*)(X + (size_t)(i0 + r) * K_DIM + kt + kq);
            As[kq+0][r] = a.x; As[kq+1][r] = a.y; As[kq+2][r] = a.z; As[kq+3][r] = a.w;
            float4 b = *(const float4*)(Y + (size_t)(j0 + r) * K_DIM + kt + kq);
            Bs[kq+0][r] = b.x; Bs[kq+1][r] = b.y; Bs[kq+2][r] = b.z; Bs[kq+3][r] = b.w;
        }
        __syncthreads();
        #pragma unroll
        for (int kk = 0; kk < 16; ++kk) {
            float a8[8], b8[8];
            #pragma unroll
            for (int u = 0; u < 8; ++u) a8[u] = As[kk][ty * 8 + u];
            #pragma unroll
            for (int v = 0; v < 8; ++v) b8[v] = Bs[kk][tx * 8 + v];
            #pragma unroll
            for (int u = 0; u < 8; ++u)
                #pragma unroll
                for (int v = 0; v < 8; ++v)
                    acc[u][v] = fmaf(a8[u], b8[v], acc[u][v]);
        }
        __syncthreads();
    }

    float lmax = 0.0f;
    #pragma unroll
    for (int u = 0; u < 8; ++u) {
        const int i = i0 + ty * 8 + u;
        const float mxi = mx[i], sxi = sx[i], x2i = x2[i];
        #pragma unroll
        for (int v = 0; v < 8; ++v) {
            const int j = j0 + tx * 8 + v;
            const float myj = my[j], syj = sy[j], y2j = y2[j];
            float corr = mxi * syj + myj * sxi - (float)K_DIM * mxi * myj;
            float d2 = x2i + y2j - 2.0f * acc[u][v] + 2.0f * corr;
            d2 = fmaxf(d2, 0.0f);
            lmax = fmaxf(lmax, d2);
            cost[(size_t)i * M_COLS + j] = sqrtf(d2);
        }
    }
    __shared__ float rmax[256];
    rmax[tid] = lmax;
    __syncthreads();
    for (int s = 128; s > 0; s >>= 1) {
        if (tid < s) rmax[tid] = fmaxf(rmax[tid], rmax[tid + s]);
        __syncthreads();
    }
    if (tid == 0) atomicMax(d2max, __float_as_uint(rmax[0]));
}

// ---------------------------------------------------------------------------
// Sinkhorn f-update: f_i = -lam*eps*(logb + log sum_j exp((g_j - cn_ij)/eps))
// one block per row
// ---------------------------------------------------------------------------
__global__ __launch_bounds__(256) void sk_f(
    const float* __restrict__ cost, const float* __restrict__ g,
    float* __restrict__ f, const float* __restrict__ params,
    const unsigned int* __restrict__ d2max)
{
    const int row = blockIdx.x, tid = threadIdx.x;
    const float invC = rsqrtf(__uint_as_float(*d2max));
    const float4* c4 = (const float4*)(cost + (size_t)row * M_COLS);
    const float4* g4 = (const float4*)g;
    float acc = 0.0f;
    #pragma unroll
    for (int rep = 0; rep < 2; ++rep) {
        int q = tid + rep * 256;               // 0..511
        float4 c = c4[q];
        float4 gg = g4[q];
        acc += __expf((gg.x - c.x * invC) * INV_EPS);
        acc += __expf((gg.y - c.y * invC) * INV_EPS);
        acc += __expf((gg.z - c.z * invC) * INV_EPS);
        acc += __expf((gg.w - c.w * invC) * INV_EPS);
    }
    __shared__ float red[256];
    red[tid] = acc;
    __syncthreads();
    for (int s = 128; s > 0; s >>= 1) {
        if (tid < s) red[tid] += red[tid + s];
        __syncthreads();
    }
    if (tid == 0) f[row] = -LAM_EPS * (params[1] + __logf(red[0]));
}

// ---------------------------------------------------------------------------
// Sinkhorn g-update partials: grid (2, 128); 64 rows per chunk, float4 cols
// ---------------------------------------------------------------------------
__global__ __launch_bounds__(256) void sk_gpart(
    const float* __restrict__ cost, const float* __restrict__ f,
    float* __restrict__ gpart, const unsigned int* __restrict__ d2max)
{
    const float invC = rsqrtf(__uint_as_float(*d2max));
    const int q  = blockIdx.x * 256 + threadIdx.x;   // 0..511 float4 col group
    const int r0 = blockIdx.y * 64;
    const float4* c4 = (const float4*)cost;
    float ax = 0.f, ay = 0.f, az = 0.f, aw = 0.f;
    for (int r = r0; r < r0 + 64; ++r) {
        const float fr = f[r];
        float4 c = c4[(size_t)r * (M_COLS / 4) + q];
        ax += __expf((fr - c.x * invC) * INV_EPS);
        ay += __expf((fr - c.y * invC) * INV_EPS);
        az += __expf((fr - c.z * invC) * INV_EPS);
        aw += __expf((fr - c.w * invC) * INV_EPS);
    }
    float4 o; o.x = ax; o.y = ay; o.z = az; o.w = aw;
    ((float4*)gpart)[(size_t)blockIdx.y * (M_COLS / 4) + q] = o;
}

// g_j = -eps*(loga + log sum_chunks gpart)
__global__ __launch_bounds__(256) void sk_gred(
    const float* __restrict__ gpart, float* __restrict__ g)
{
    const int col = blockIdx.x * 256 + threadIdx.x;
    float s = 0.0f;
    for (int c = 0; c < 128; ++c) s += gpart[(size_t)c * M_COLS + col];
    g[col] = -dEPS() * (LOGA + __logf(s));
}

// ---------------------------------------------------------------------------
// final: flow = exp((f+g-cn)/eps + loga + logb)/rho  (in-place over cost),
// dist += sum(cn * flow)
// ---------------------------------------------------------------------------
__global__ __launch_bounds__(256) void flow_dist(
    float* buf /* cost in, flow out */, const float* __restrict__ f,
    const float* __restrict__ g, const float* __restrict__ params,
    const unsigned int* __restrict__ d2max, float* dist)
{
    const int tid = threadIdx.x;
    const float invC = rsqrtf(__uint_as_float(*d2max));
    const float rho = params[0];
    const float c1 = LOGA + params[1];       // loga + logb
    const float invRho = 1.0f / rho;
    float4* b4 = (float4*)buf;
    const float4* g4 = (const float4*)g;
    const size_t total = NM / 4;             // float4 elements
    const size_t stride = (size_t)gridDim.x * blockDim.x;
    float local = 0.0f;
    for (size_t q = (size_t)blockIdx.x * blockDim.x + tid; q < total; q += stride) {
        const int i  = (int)(q >> 9);        // 512 float4 per row
        const int jq = (int)(q & 511);
        const float fi = f[i];
        float4 c = b4[q];
        float4 gg = g4[jq];
        float4 o;
        float cn;
        cn = c.x * invC; o.x = __expf((fi + gg.x - cn) * INV_EPS + c1) * invRho; local += cn * o.x;
        cn = c.y * invC; o.y = __expf((fi + gg.y - cn) * INV_EPS + c1) * invRho; local += cn * o.y;
        cn = c.z * invC; o.z = __expf((fi + gg.z - cn) * INV_EPS + c1) * invRho; local += cn * o.z;
        cn = c.w * invC; o.w = __expf((fi + gg.w - cn) * INV_EPS + c1) * invRho; local += cn * o.w;
        b4[q] = o;
    }
    __shared__ float red[256];
    red[tid] = local;
    __syncthreads();
    for (int s = 128; s > 0; s >>= 1) {
        if (tid < s) red[tid] += red[tid + s];
        __syncthreads();
    }
    if (tid == 0) atomicAdd(dist, red[0]);
}

// ---------------------------------------------------------------------------
extern "C" void kernel_launch(void* const* d_in, const int* in_sizes, int n_in,
                              void* d_out, int out_size, void* d_ws, size_t ws_size,
                              hipStream_t stream)
{
    const float* x     = (const float*)d_in[0];
    const float* y     = (const float*)d_in[1];
    const int*   iters = (const int*)d_in[2];
    const int*   ipe   = (const int*)d_in[3];
    float* out = (float*)d_out;
    float* ws  = (float*)d_ws;

    // ws layout (floats)
    float*        params = ws;                       // [0]=rho [1]=logb
    unsigned int* d2max  = (unsigned int*)(ws + 8);
    float* f  = ws + 16;                             // 8192
    float* g  = f + N_ROWS;                          // 2048
    float* mx = g + M_COLS;                          // 8192
    float* sx = mx + N_ROWS;                         // 8192
    float* x2 = sx + N_ROWS;                         // 8192
    float* my = x2 + N_ROWS;                         // 2048
    float* sy = my + M_COLS;                         // 2048
    float* y2 = sy + M_COLS;                         // 2048
    float* gpart = y2 + M_COLS;                      // 128*2048

    float* cost = out;                               // cost lives in flow slot
    float* dist = out + NM;

    hipMemsetAsync(d2max, 0, sizeof(unsigned int), stream);
    hipMemsetAsync(g, 0, M_COLS * sizeof(float), stream);
    hipMemsetAsync(dist, 0, sizeof(float), stream);

    k_params<<<1, 64, 0, stream>>>(iters, ipe, params);
    rowstats<<<N_ROWS, 256, 0, stream>>>(x, mx, sx, x2);
    rowstats<<<M_COLS, 256, 0, stream>>>(y, my, sy, y2);
    gemm_cost<<<dim3(M_COLS / 128, N_ROWS / 128), 256, 0, stream>>>(
        x, y, mx, sx, x2, my, sy, y2, cost, d2max);
    for (int it = 0; it < 3; ++it) {
        sk_f<<<N_ROWS, 256, 0, stream>>>(cost, g, f, params, d2max);
        sk_gpart<<<dim3(2, 128), 256, 0, stream>>>(cost, f, gpart, d2max);
        sk_gred<<<M_COLS / 256, 256, 0, stream>>>(gpart, g);
    }
    flow_dist<<<4096, 256, 0, stream>>>(cost, f, g, params, d2max, dist);
}

// Round 2
// 423.537 us; speedup vs baseline: 1.6914x; 1.6914x over previous
//
#include <hip/hip_runtime.h>
#include <math.h>

// Problem constants
#define N_ROWS 8192
#define M_COLS 2048
#define K_DIM  1024
#define NM     ((size_t)N_ROWS * M_COLS)

#define INV_EPS   10.0f
#define EPSV      0.1f
#define LAM_EPS   (0.1f/1.1f)                 // (GAMMA/(GAMMA+EPS))*EPS
#define LOGA      (-9.010913347279288f)       // -log(8192)
#define LOG_M     (7.624618986159398f)        // log(2048)

#define SK_BLOCKS 256
#define ROWS_PER_SK (N_ROWS / SK_BLOCKS)      // 32

typedef __bf16 bf16x8 __attribute__((ext_vector_type(8)));
typedef float  f32x4  __attribute__((ext_vector_type(4)));
typedef unsigned short u16x8 __attribute__((ext_vector_type(8)));

// ---------------------------------------------------------------------------
// params: rho + logb from device scalars
// ---------------------------------------------------------------------------
__global__ void k_params(const int* __restrict__ iters, const int* __restrict__ ipe,
                         float* __restrict__ params)
{
    if (threadIdx.x == 0) {
        float ramp = 10.0f * (float)ipe[0];
        float rho;
        if (ramp == 0.0f) {
            rho = 1.0f + 0.1f;
        } else {
            float cur = fminf(fmaxf((float)iters[0], 0.0f), ramp);
            float phase = 1.0f - cur / ramp;
            rho = expf(-5.0f * phase * phase) * 1.0f + 0.1f;
        }
        rho = fminf(rho, 1.0f);
        params[0] = rho;
        params[1] = logf(rho) - LOG_M;   // logb
    }
}

// ---------------------------------------------------------------------------
// per-row stats: min, sum, and normalized sumsq  (cols == 1024, 256 thr/blk)
// ---------------------------------------------------------------------------
__global__ __launch_bounds__(256) void rowstats(
    const float* __restrict__ A, float* __restrict__ mn,
    float* __restrict__ sm, float* __restrict__ s2n)
{
    const int row = blockIdx.x, tid = threadIdx.x;
    const float4 v = ((const float4*)(A + (size_t)row * K_DIM))[tid];
    float lmin = fminf(fminf(v.x, v.y), fminf(v.z, v.w));
    float lsum = v.x + v.y + v.z + v.w;
    float lsq  = v.x*v.x + v.y*v.y + v.z*v.z + v.w*v.w;

    __shared__ float rmin[256], rsum[256], rsq[256];
    rmin[tid] = lmin; rsum[tid] = lsum; rsq[tid] = lsq;
    __syncthreads();
    for (int s = 128; s > 0; s >>= 1) {
        if (tid < s) {
            rmin[tid] = fminf(rmin[tid], rmin[tid + s]);
            rsum[tid] += rsum[tid + s];
            rsq[tid]  += rsq[tid + s];
        }
        __syncthreads();
    }
    if (tid == 0) {
        float m = rmin[0], s = rsum[0], q = rsq[0];
        mn[row]  = m;
        sm[row]  = s;
        s2n[row] = q - 2.0f * m * s + (float)K_DIM * m * m;  // ||a - m||^2
    }
}

// ---------------------------------------------------------------------------
// bf16 split helpers (RNE)
// ---------------------------------------------------------------------------
static __device__ __forceinline__ unsigned short f2bf_rne(float x) {
    unsigned u = __float_as_uint(x);
    u += 0x7FFFu + ((u >> 16) & 1u);
    return (unsigned short)(u >> 16);
}

static __device__ __forceinline__ void cvt_store(
    unsigned short* __restrict__ ph, unsigned short* __restrict__ pl, float4 v)
{
    ushort4 h, l;
    h.x = f2bf_rne(v.x); l.x = f2bf_rne(v.x - __uint_as_float((unsigned)h.x << 16));
    h.y = f2bf_rne(v.y); l.y = f2bf_rne(v.y - __uint_as_float((unsigned)h.y << 16));
    h.z = f2bf_rne(v.z); l.z = f2bf_rne(v.z - __uint_as_float((unsigned)h.z << 16));
    h.w = f2bf_rne(v.w); l.w = f2bf_rne(v.w - __uint_as_float((unsigned)h.w << 16));
    *(ushort4*)ph = h;
    *(ushort4*)pl = l;
}

static __device__ __forceinline__ bf16x8 lds_frag(const unsigned short* p) {
    return __builtin_bit_cast(bf16x8, *(const u16x8*)p);
}

// ---------------------------------------------------------------------------
// MFMA GEMM + cost epilogue.
// 128x128 tile, 256 threads = 4 waves (2x2 of 64x64), BK=32.
// dot = xh*yh + xl*yh + xh*yl  (split-bf16, fp32-equivalent accuracy)
// cost[i][j] = sqrt(max(d2,0)); track global max(d2).
// ---------------------------------------------------------------------------
__global__ __launch_bounds__(256) void gemm_cost_mfma(
    const float* __restrict__ X, const float* __restrict__ Y,
    const float* __restrict__ mx, const float* __restrict__ sx, const float* __restrict__ x2,
    const float* __restrict__ my, const float* __restrict__ sy, const float* __restrict__ y2,
    float* __restrict__ cost, unsigned int* __restrict__ d2max)
{
    __shared__ unsigned short Ah[128][32];
    __shared__ unsigned short Al[128][32];
    __shared__ unsigned short Bh[128][32];
    __shared__ unsigned short Bl[128][32];
    __shared__ float rmax[256];

    const int tid   = threadIdx.x;
    const int lane  = tid & 63;
    const int wave  = tid >> 6;
    const int wi    = wave >> 1;          // 0..1
    const int wj    = wave & 1;           // 0..1
    const int row16 = lane & 15;
    const int quad  = lane >> 4;          // 0..3
    const int i0 = blockIdx.y * 128, j0 = blockIdx.x * 128;

    f32x4 acc[4][4];
    #pragma unroll
    for (int u = 0; u < 4; ++u)
        #pragma unroll
        for (int v = 0; v < 4; ++v) acc[u][v] = (f32x4){0.f, 0.f, 0.f, 0.f};

    for (int kt = 0; kt < K_DIM; kt += 32) {
        // stage 128x32 fp32 of X and Y -> bf16 hi/lo in LDS
        #pragma unroll
        for (int rep = 0; rep < 4; ++rep) {
            const int s  = tid + rep * 256;    // 0..1023
            const int r  = s >> 3;             // 0..127
            const int kq = (s & 7) << 2;       // 0,4,...,28
            float4 a = *(const float4*)(X + (size_t)(i0 + r) * K_DIM + kt + kq);
            cvt_store(&Ah[r][kq], &Al[r][kq], a);
            float4 b = *(const float4*)(Y + (size_t)(j0 + r) * K_DIM + kt + kq);
            cvt_store(&Bh[r][kq], &Bl[r][kq], b);
        }
        __syncthreads();

        bf16x8 afh[4], afl[4], bfh[4], bfl[4];
        #pragma unroll
        for (int t = 0; t < 4; ++t) {
            const int ar = wi * 64 + t * 16 + row16;
            afh[t] = lds_frag(&Ah[ar][quad * 8]);
            afl[t] = lds_frag(&Al[ar][quad * 8]);
            const int br = wj * 64 + t * 16 + row16;
            bfh[t] = lds_frag(&Bh[br][quad * 8]);
            bfl[t] = lds_frag(&Bl[br][quad * 8]);
        }
        #pragma unroll
        for (int ti = 0; ti < 4; ++ti) {
            #pragma unroll
            for (int tj = 0; tj < 4; ++tj) {
                acc[ti][tj] = __builtin_amdgcn_mfma_f32_16x16x32_bf16(
                    afh[ti], bfh[tj], acc[ti][tj], 0, 0, 0);
                acc[ti][tj] = __builtin_amdgcn_mfma_f32_16x16x32_bf16(
                    afl[ti], bfh[tj], acc[ti][tj], 0, 0, 0);
                acc[ti][tj] = __builtin_amdgcn_mfma_f32_16x16x32_bf16(
                    afh[ti], bfl[tj], acc[ti][tj], 0, 0, 0);
            }
        }
        __syncthreads();
    }

    // epilogue: C/D layout col=lane&15, row=quad*4+reg
    float lmax = 0.0f;
    float myj[4], syj[4], yy[4];
    #pragma unroll
    for (int tj = 0; tj < 4; ++tj) {
        const int j = j0 + wj * 64 + tj * 16 + row16;
        myj[tj] = my[j]; syj[tj] = sy[j]; yy[tj] = y2[j];
    }
    #pragma unroll
    for (int ti = 0; ti < 4; ++ti) {
        #pragma unroll
        for (int reg = 0; reg < 4; ++reg) {
            const int i = i0 + wi * 64 + ti * 16 + quad * 4 + reg;
            const float mxi = mx[i], sxi = sx[i], xxi = x2[i];
            #pragma unroll
            for (int tj = 0; tj < 4; ++tj) {
                const int j = j0 + wj * 64 + tj * 16 + row16;
                float corr = mxi * syj[tj] + myj[tj] * sxi - (float)K_DIM * mxi * myj[tj];
                float d2 = xxi + yy[tj] - 2.0f * acc[ti][tj][reg] + 2.0f * corr;
                d2 = fmaxf(d2, 0.0f);
                lmax = fmaxf(lmax, d2);
                cost[(size_t)i * M_COLS + j] = sqrtf(d2);
            }
        }
    }
    rmax[tid] = lmax;
    __syncthreads();
    for (int s = 128; s > 0; s >>= 1) {
        if (tid < s) rmax[tid] = fmaxf(rmax[tid], rmax[tid + s]);
        __syncthreads();
    }
    if (tid == 0) atomicMax(d2max, __float_as_uint(rmax[0]));
}

// ---------------------------------------------------------------------------
// Fused Sinkhorn iteration: for each of this block's rows,
//   f_i = -lam*eps*(logb + log sum_j exp((g_j - cn_ij)/eps))
// then accumulate per-column partials  sum_i exp((f_i - cn_ij)/eps).
// Cost row is read once and held in registers across both passes.
// grid = 256 blocks x 256 threads; block handles 32 rows.
// ---------------------------------------------------------------------------
__global__ __launch_bounds__(256) void sk_iter(
    const float* __restrict__ cost, const float* __restrict__ g,
    float* __restrict__ f, float* __restrict__ gpart,
    const float* __restrict__ params, const unsigned int* __restrict__ d2max)
{
    const int tid  = threadIdx.x;
    const int lane = tid & 63;
    const int wave = tid >> 6;
    const float invC = rsqrtf(__uint_as_float(*d2max));
    const float logb = params[1];

    __shared__ float red[2][4];

    const float4* g4 = (const float4*)g;
    const float4 g0 = g4[tid];
    const float4 g1 = g4[tid + 256];

    float4 p0 = {0.f, 0.f, 0.f, 0.f};
    float4 p1 = {0.f, 0.f, 0.f, 0.f};

    const int r0 = blockIdx.x * ROWS_PER_SK;
    const float4* c4 = (const float4*)cost;
    size_t base = (size_t)r0 * (M_COLS / 4);

    float4 c0 = c4[base + tid];
    float4 c1 = c4[base + 256 + tid];

    for (int rr = 0; rr < ROWS_PER_SK; ++rr) {
        float4 n0, n1;
        if (rr < ROWS_PER_SK - 1) {
            n0 = c4[base + (size_t)(rr + 1) * 512 + tid];
            n1 = c4[base + (size_t)(rr + 1) * 512 + 256 + tid];
        }
        // pass A: row logsumexp (no max-sub; exponents are in safe range)
        float acc = __expf((g0.x - c0.x * invC) * INV_EPS)
                  + __expf((g0.y - c0.y * invC) * INV_EPS)
                  + __expf((g0.z - c0.z * invC) * INV_EPS)
                  + __expf((g0.w - c0.w * invC) * INV_EPS)
                  + __expf((g1.x - c1.x * invC) * INV_EPS)
                  + __expf((g1.y - c1.y * invC) * INV_EPS)
                  + __expf((g1.z - c1.z * invC) * INV_EPS)
                  + __expf((g1.w - c1.w * invC) * INV_EPS);
        #pragma unroll
        for (int off = 32; off > 0; off >>= 1)
            acc += __shfl_xor(acc, off, 64);
        if (lane == 0) red[rr & 1][wave] = acc;
        __syncthreads();
        float tot = red[rr & 1][0] + red[rr & 1][1] + red[rr & 1][2] + red[rr & 1][3];
        float fr = -LAM_EPS * (logb + __logf(tot));
        if (tid == 0) f[r0 + rr] = fr;
        // pass B: column partials with fresh f
        p0.x += __expf((fr - c0.x * invC) * INV_EPS);
        p0.y += __expf((fr - c0.y * invC) * INV_EPS);
        p0.z += __expf((fr - c0.z * invC) * INV_EPS);
        p0.w += __expf((fr - c0.w * invC) * INV_EPS);
        p1.x += __expf((fr - c1.x * invC) * INV_EPS);
        p1.y += __expf((fr - c1.y * invC) * INV_EPS);
        p1.z += __expf((fr - c1.z * invC) * INV_EPS);
        p1.w += __expf((fr - c1.w * invC) * INV_EPS);
        c0 = n0; c1 = n1;
    }
    float4* gp4 = (float4*)gpart;
    gp4[(size_t)blockIdx.x * (M_COLS / 4) + tid]       = p0;
    gp4[(size_t)blockIdx.x * (M_COLS / 4) + 256 + tid] = p1;
}

// g_j = -eps*(loga + log sum_chunks gpart)
// grid 32 blocks; 256 threads = 64 cols x 4 chunk-quarters
__global__ __launch_bounds__(256) void sk_gred(
    const float* __restrict__ gpart, float* __restrict__ g)
{
    const int tid = threadIdx.x;
    const int col = blockIdx.x * 64 + (tid & 63);
    const int cq  = tid >> 6;            // 0..3
    float s = 0.0f;
    for (int c = cq * 64; c < cq * 64 + 64; ++c)
        s += gpart[(size_t)c * M_COLS + col];
    __shared__ float sh[256];
    sh[tid] = s;
    __syncthreads();
    if (tid < 64) {
        float t = sh[tid] + sh[tid + 64] + sh[tid + 128] + sh[tid + 192];
        g[col] = -EPSV * (LOGA + __logf(t));
    }
}

// ---------------------------------------------------------------------------
// final: flow = exp((f+g-cn)/eps + loga + logb)/rho  (in-place over cost),
// dist += sum(cn * flow)
// ---------------------------------------------------------------------------
__global__ __launch_bounds__(256) void flow_dist(
    float* buf /* cost in, flow out */, const float* __restrict__ f,
    const float* __restrict__ g, const float* __restrict__ params,
    const unsigned int* __restrict__ d2max, float* dist)
{
    const int tid = threadIdx.x;
    const float invC = rsqrtf(__uint_as_float(*d2max));
    const float rho = params[0];
    const float c1 = LOGA + params[1];       // loga + logb
    const float invRho = 1.0f / rho;
    float4* b4 = (float4*)buf;
    const float4* g4 = (const float4*)g;
    const size_t total = NM / 4;             // float4 elements
    const size_t stride = (size_t)gridDim.x * blockDim.x;
    float local = 0.0f;
    for (size_t q = (size_t)blockIdx.x * blockDim.x + tid; q < total; q += stride) {
        const int i  = (int)(q >> 9);        // 512 float4 per row
        const int jq = (int)(q & 511);
        const float fi = f[i];
        float4 c = b4[q];
        float4 gg = g4[jq];
        float4 o;
        float cn;
        cn = c.x * invC; o.x = __expf((fi + gg.x - cn) * INV_EPS + c1) * invRho; local += cn * o.x;
        cn = c.y * invC; o.y = __expf((fi + gg.y - cn) * INV_EPS + c1) * invRho; local += cn * o.y;
        cn = c.z * invC; o.z = __expf((fi + gg.z - cn) * INV_EPS + c1) * invRho; local += cn * o.z;
        cn = c.w * invC; o.w = __expf((fi + gg.w - cn) * INV_EPS + c1) * invRho; local += cn * o.w;
        b4[q] = o;
    }
    __shared__ float red[256];
    red[tid] = local;
    __syncthreads();
    for (int s = 128; s > 0; s >>= 1) {
        if (tid < s) red[tid] += red[tid + s];
        __syncthreads();
    }
    if (tid == 0) atomicAdd(dist, red[0]);
}

// ---------------------------------------------------------------------------
extern "C" void kernel_launch(void* const* d_in, const int* in_sizes, int n_in,
                              void* d_out, int out_size, void* d_ws, size_t ws_size,
                              hipStream_t stream)
{
    const float* x     = (const float*)d_in[0];
    const float* y     = (const float*)d_in[1];
    const int*   iters = (const int*)d_in[2];
    const int*   ipe   = (const int*)d_in[3];
    float* out = (float*)d_out;
    float* ws  = (float*)d_ws;

    // ws layout (floats)
    float*        params = ws;                       // [0]=rho [1]=logb
    unsigned int* d2max  = (unsigned int*)(ws + 8);
    float* f  = ws + 16;                             // 8192
    float* g  = f + N_ROWS;                          // 2048
    float* mx = g + M_COLS;                          // 8192
    float* sx = mx + N_ROWS;                         // 8192
    float* x2 = sx + N_ROWS;                         // 8192
    float* my = x2 + N_ROWS;                         // 2048
    float* sy = my + M_COLS;                         // 2048
    float* y2 = sy + M_COLS;                         // 2048
    float* gpart = y2 + M_COLS;                      // SK_BLOCKS*2048 = 2 MB

    float* cost = out;                               // cost lives in flow slot
    float* dist = out + NM;

    hipMemsetAsync(d2max, 0, sizeof(unsigned int), stream);
    hipMemsetAsync(g, 0, M_COLS * sizeof(float), stream);
    hipMemsetAsync(dist, 0, sizeof(float), stream);

    k_params<<<1, 64, 0, stream>>>(iters, ipe, params);
    rowstats<<<N_ROWS, 256, 0, stream>>>(x, mx, sx, x2);
    rowstats<<<M_COLS, 256, 0, stream>>>(y, my, sy, y2);
    gemm_cost_mfma<<<dim3(M_COLS / 128, N_ROWS / 128), 256, 0, stream>>>(
        x, y, mx, sx, x2, my, sy, y2, cost, d2max);
    for (int it = 0; it < 3; ++it) {
        sk_iter<<<SK_BLOCKS, 256, 0, stream>>>(cost, g, f, gpart, params, d2max);
        sk_gred<<<M_COLS / 64, 256, 0, stream>>>(gpart, g);
    }
    flow_dist<<<4096, 256, 0, stream>>>(cost, f, g, params, d2max, dist);
}

// Round 3
// 398.154 us; speedup vs baseline: 1.7993x; 1.0638x over previous
//
#include <hip/hip_runtime.h>
#include <math.h>

// Problem constants
#define N_ROWS 8192
#define M_COLS 2048
#define K_DIM  1024
#define NM     ((size_t)N_ROWS * M_COLS)

#define LAM       0.9090909090909091f         // GAMMA/(GAMMA+EPS)
#define LOG_M     7.624618986159398f          // log(2048)

#define BM 256
#define BN 128
#define LDP 40                                 // LDS pitch (shorts): 80 B rows, 16B-aligned, bank-spread

#define SKB 512                                // sinkhorn blocks
#define RPB (N_ROWS / SKB)                     // 16 rows per block

typedef __bf16 bf16x8 __attribute__((ext_vector_type(8)));
typedef float  f32x4  __attribute__((ext_vector_type(4)));
typedef unsigned short u16x8 __attribute__((ext_vector_type(8)));
typedef _Float16 h8 __attribute__((ext_vector_type(8)));

// ---------------------------------------------------------------------------
// init: rho/logb params + u = 1 (g = 0)
// ---------------------------------------------------------------------------
__global__ void k_init(const int* __restrict__ iters, const int* __restrict__ ipe,
                       float* __restrict__ params, float* __restrict__ u)
{
    const int t = blockIdx.x * 256 + threadIdx.x;
    if (t < M_COLS) u[t] = 1.0f;
    if (t == 0) {
        float ramp = 10.0f * (float)ipe[0];
        float rho;
        if (ramp == 0.0f) {
            rho = 1.1f;
        } else {
            float cur = fminf(fmaxf((float)iters[0], 0.0f), ramp);
            float phase = 1.0f - cur / ramp;
            rho = expf(-5.0f * phase * phase) + 0.1f;
        }
        rho = fminf(rho, 1.0f);
        params[0] = rho;
        params[1] = logf(rho) - LOG_M;   // logb = log(rho/M)
    }
}

// ---------------------------------------------------------------------------
// per-row stats: min, sum, normalized sumsq  (K=1024, 256 thr/blk)
// ---------------------------------------------------------------------------
__global__ __launch_bounds__(256) void rowstats(
    const float* __restrict__ A, float* __restrict__ mn,
    float* __restrict__ sm, float* __restrict__ s2n)
{
    const int row = blockIdx.x, tid = threadIdx.x;
    const float4 v = ((const float4*)(A + (size_t)row * K_DIM))[tid];
    float lmin = fminf(fminf(v.x, v.y), fminf(v.z, v.w));
    float lsum = v.x + v.y + v.z + v.w;
    float lsq  = v.x*v.x + v.y*v.y + v.z*v.z + v.w*v.w;

    __shared__ float rmin[256], rsum[256], rsq[256];
    rmin[tid] = lmin; rsum[tid] = lsum; rsq[tid] = lsq;
    __syncthreads();
    for (int s = 128; s > 0; s >>= 1) {
        if (tid < s) {
            rmin[tid] = fminf(rmin[tid], rmin[tid + s]);
            rsum[tid] += rsum[tid + s];
            rsq[tid]  += rsq[tid + s];
        }
        __syncthreads();
    }
    if (tid == 0) {
        float m = rmin[0], s = rsum[0], q = rsq[0];
        mn[row]  = m;
        sm[row]  = s;
        s2n[row] = q - 2.0f * m * s + (float)K_DIM * m * m;  // ||a - m||^2
    }
}

// ---------------------------------------------------------------------------
// fp32 pair -> packed bf16 (RNE)
// ---------------------------------------------------------------------------
static __device__ __forceinline__ unsigned pk_bf16(float a, float b) {
#if __has_builtin(__builtin_amdgcn_cvt_pk_bf16_f32)
    typedef __bf16 bf16x2 __attribute__((ext_vector_type(2)));
    bf16x2 r = __builtin_amdgcn_cvt_pk_bf16_f32(a, b);
    return __builtin_bit_cast(unsigned, r);
#else
    unsigned ua = __float_as_uint(a), ub = __float_as_uint(b);
    ua += 0x7FFFu + ((ua >> 16) & 1u);
    ub += 0x7FFFu + ((ub >> 16) & 1u);
    return (ua >> 16) | (ub & 0xFFFF0000u);
#endif
}

static __device__ __forceinline__ bf16x8 lds_frag(const unsigned short* p) {
    return __builtin_bit_cast(bf16x8, *(const u16x8*)p);
}

// ---------------------------------------------------------------------------
// MFMA GEMM + cost epilogue, hi-only bf16.
// 256x128 tile, 4 waves (64 rows x 128 cols each), BK=32, 16x16x32 MFMA.
// cost[i][j] = sqrt(max(d2,0)); track global max(d2).
// ---------------------------------------------------------------------------
__global__ __launch_bounds__(256, 2) void gemm_cost_mfma(
    const float* __restrict__ X, const float* __restrict__ Y,
    const float* __restrict__ mx, const float* __restrict__ sx, const float* __restrict__ x2,
    const float* __restrict__ my, const float* __restrict__ sy, const float* __restrict__ y2,
    float* __restrict__ cost, unsigned int* __restrict__ d2max)
{
    __shared__ unsigned short Ah[BM][LDP];   // 20480 B
    __shared__ unsigned short Bh[BN][LDP];   // 10240 B
    __shared__ float rmax[256];

    const int tid   = threadIdx.x;
    const int lane  = tid & 63;
    const int wave  = tid >> 6;           // row group 0..3
    const int row16 = lane & 15;
    const int quad  = lane >> 4;          // 0..3
    const int i0 = blockIdx.y * BM, j0 = blockIdx.x * BN;

    f32x4 acc[4][8];
    #pragma unroll
    for (int u = 0; u < 4; ++u)
        #pragma unroll
        for (int v = 0; v < 8; ++v) acc[u][v] = (f32x4){0.f, 0.f, 0.f, 0.f};

    for (int kt = 0; kt < K_DIM; kt += 32) {
        // stage A: 256 rows x 32 k (8 reps), B: 128 rows x 32 k (4 reps)
        #pragma unroll
        for (int rep = 0; rep < 8; ++rep) {
            const int id = tid + rep * 256;        // 0..2047
            const int r  = id >> 3;                // 0..255
            const int kq = (id & 7) << 2;          // 0..28
            float4 a = *(const float4*)(X + (size_t)(i0 + r) * K_DIM + kt + kq);
            uint2 pa; pa.x = pk_bf16(a.x, a.y); pa.y = pk_bf16(a.z, a.w);
            *(uint2*)&Ah[r][kq] = pa;
        }
        #pragma unroll
        for (int rep = 0; rep < 4; ++rep) {
            const int id = tid + rep * 256;        // 0..1023
            const int r  = id >> 3;                // 0..127
            const int kq = (id & 7) << 2;
            float4 b = *(const float4*)(Y + (size_t)(j0 + r) * K_DIM + kt + kq);
            uint2 pb; pb.x = pk_bf16(b.x, b.y); pb.y = pk_bf16(b.z, b.w);
            *(uint2*)&Bh[r][kq] = pb;
        }
        __syncthreads();

        bf16x8 af[4], bf[8];
        #pragma unroll
        for (int t = 0; t < 4; ++t)
            af[t] = lds_frag(&Ah[wave * 64 + t * 16 + row16][quad * 8]);
        #pragma unroll
        for (int t = 0; t < 8; ++t)
            bf[t] = lds_frag(&Bh[t * 16 + row16][quad * 8]);

        #pragma unroll
        for (int ti = 0; ti < 4; ++ti)
            #pragma unroll
            for (int tj = 0; tj < 8; ++tj)
                acc[ti][tj] = __builtin_amdgcn_mfma_f32_16x16x32_bf16(
                    af[ti], bf[tj], acc[ti][tj], 0, 0, 0);
        __syncthreads();
    }

    // epilogue: C/D layout col=lane&15 (j), row=quad*4+reg (i)
    float lmax = 0.0f;
    float myj[8], syj[8], yy[8];
    #pragma unroll
    for (int tj = 0; tj < 8; ++tj) {
        const int j = j0 + tj * 16 + row16;
        myj[tj] = my[j]; syj[tj] = sy[j]; yy[tj] = y2[j];
    }
    #pragma unroll
    for (int ti = 0; ti < 4; ++ti) {
        #pragma unroll
        for (int reg = 0; reg < 4; ++reg) {
            const int i = i0 + wave * 64 + ti * 16 + quad * 4 + reg;
            const float mxi = mx[i], sxi = sx[i], xxi = x2[i];
            #pragma unroll
            for (int tj = 0; tj < 8; ++tj) {
                const int j = j0 + tj * 16 + row16;
                float corr = mxi * syj[tj] + myj[tj] * sxi - (float)K_DIM * mxi * myj[tj];
                float d2 = xxi + yy[tj] - 2.0f * acc[ti][tj][reg] + 2.0f * corr;
                d2 = fmaxf(d2, 0.0f);
                lmax = fmaxf(lmax, d2);
                cost[(size_t)i * M_COLS + j] = sqrtf(d2);
            }
        }
    }
    rmax[tid] = lmax;
    __syncthreads();
    for (int s = 128; s > 0; s >>= 1) {
        if (tid < s) rmax[tid] = fmaxf(rmax[tid], rmax[tid + s]);
        __syncthreads();
    }
    if (tid == 0) atomicMax(d2max, __float_as_uint(rmax[0]));
}

// ---------------------------------------------------------------------------
// Sinkhorn iteration on E = exp(-10*cn), all matvec (FMA-only inner loops).
//   t_r = sum_j E_rj u_j ; w_r = exp(-LAM*(logb + ln t_r))
//   gpart[b][j] = sum_{r in block} E_rj w_r     (fp16 partials)
// FIRST=true additionally converts fp32 cost -> fp16 E in-place in d_out.
// E row r lives at halfptr = (half*)out + r*4096 (first half of cost row).
// 512 blocks x 256 threads; block = 16 rows; thread = 8 contiguous cols.
// ---------------------------------------------------------------------------
template<bool FIRST>
__global__ __launch_bounds__(256) void sk_iter(
    float* __restrict__ outbuf, const float* __restrict__ u,
    float* __restrict__ w, _Float16* __restrict__ gpart,
    const float* __restrict__ params, const unsigned int* __restrict__ d2max)
{
    const int tid  = threadIdx.x;
    const int lane = tid & 63;
    const int wave = tid >> 6;
    const int r0   = blockIdx.x * RPB;
    const float logb = params[1];

    _Float16* Eb = (_Float16*)outbuf;
    h8 E[RPB];

    if (FIRST) {
        const float invC10 = 10.0f * rsqrtf(__uint_as_float(*d2max));
        #pragma unroll
        for (int r = 0; r < RPB; ++r) {
            const float* crow = outbuf + (size_t)(r0 + r) * M_COLS + 8 * tid;
            float4 c0 = *(const float4*)crow;
            float4 c1 = *(const float4*)(crow + 4);
            h8 e;
            e[0] = (_Float16)__expf(-c0.x * invC10);
            e[1] = (_Float16)__expf(-c0.y * invC10);
            e[2] = (_Float16)__expf(-c0.z * invC10);
            e[3] = (_Float16)__expf(-c0.w * invC10);
            e[4] = (_Float16)__expf(-c1.x * invC10);
            e[5] = (_Float16)__expf(-c1.y * invC10);
            e[6] = (_Float16)__expf(-c1.z * invC10);
            e[7] = (_Float16)__expf(-c1.w * invC10);
            E[r] = e;
        }
        __syncthreads();   // all cost reads done before E overwrites
        #pragma unroll
        for (int r = 0; r < RPB; ++r)
            *(uint4*)(Eb + (size_t)(r0 + r) * 4096 + 8 * tid) = __builtin_bit_cast(uint4, E[r]);
    } else {
        #pragma unroll
        for (int r = 0; r < RPB; ++r)
            E[r] = __builtin_bit_cast(h8, *(const uint4*)(Eb + (size_t)(r0 + r) * 4096 + 8 * tid));
    }

    float4 ua = *(const float4*)(u + 8 * tid);
    float4 ub = *(const float4*)(u + 8 * tid + 4);
    float u8[8] = {ua.x, ua.y, ua.z, ua.w, ub.x, ub.y, ub.z, ub.w};

    // pass A: row sums t_r
    float pr[RPB];
    #pragma unroll
    for (int r = 0; r < RPB; ++r) {
        float s = 0.0f;
        #pragma unroll
        for (int c = 0; c < 8; ++c) s += (float)E[r][c] * u8[c];
        pr[r] = s;
    }
    #pragma unroll
    for (int r = 0; r < RPB; ++r)
        #pragma unroll
        for (int off = 32; off > 0; off >>= 1)
            pr[r] += __shfl_xor(pr[r], off, 64);

    __shared__ float R[RPB][4];
    __shared__ float W[RPB];
    if (lane == 0)
        #pragma unroll
        for (int r = 0; r < RPB; ++r) R[r][wave] = pr[r];
    __syncthreads();
    if (tid < RPB) {
        float t = R[tid][0] + R[tid][1] + R[tid][2] + R[tid][3];
        float wr = __expf(-LAM * (logb + __logf(t)));
        W[tid] = wr;
        w[r0 + tid] = wr;
    }
    __syncthreads();

    // pass B: column partials sum_r E*w
    float p[8] = {0.f, 0.f, 0.f, 0.f, 0.f, 0.f, 0.f, 0.f};
    #pragma unroll
    for (int r = 0; r < RPB; ++r) {
        const float wr = W[r];
        #pragma unroll
        for (int c = 0; c < 8; ++c) p[c] += (float)E[r][c] * wr;
    }
    h8 ph;
    #pragma unroll
    for (int c = 0; c < 8; ++c) ph[c] = (_Float16)p[c];
    *(uint4*)(gpart + (size_t)blockIdx.x * M_COLS + 8 * tid) = __builtin_bit_cast(uint4, ph);
}

// u_j = N / sigma_j,  sigma_j = sum_blocks gpart
__global__ __launch_bounds__(256) void sk_gred(
    const _Float16* __restrict__ gpart, float* __restrict__ u)
{
    const int col = blockIdx.x * 256 + threadIdx.x;
    float s = 0.0f;
    #pragma unroll 8
    for (int b = 0; b < SKB; ++b) s += (float)gpart[(size_t)b * M_COLS + col];
    u[col] = (float)N_ROWS / s;
}

// ---------------------------------------------------------------------------
// flow = E * w_r * u_j / (N*M)  (in-place: fp16 E -> fp32 flow in d_out)
// dist += sum cn * flow,  cn = -0.1*ln(E)
// ---------------------------------------------------------------------------
__global__ __launch_bounds__(256) void flow_dist(
    float* __restrict__ outbuf, const float* __restrict__ w,
    const float* __restrict__ u, float* __restrict__ dist)
{
    const int tid = threadIdx.x;
    const int r0  = blockIdx.x * RPB;
    const float invNM = 1.0f / ((float)N_ROWS * (float)M_COLS);
    _Float16* Eb = (_Float16*)outbuf;

    float4 uA = *(const float4*)(u + 8 * tid);
    float4 uB = *(const float4*)(u + 8 * tid + 4);
    float u8[8] = {uA.x, uA.y, uA.z, uA.w, uB.x, uB.y, uB.z, uB.w};

    float local = 0.0f;
    for (int r = 0; r < RPB; ++r) {
        const int row = r0 + r;
        h8 E = __builtin_bit_cast(h8, *(const uint4*)(Eb + (size_t)row * 4096 + 8 * tid));
        const float wr = w[row];
        float fl[8];
        #pragma unroll
        for (int c = 0; c < 8; ++c) {
            float e = (float)E[c];
            float o = e * wr * u8[c] * invNM;
            fl[c] = o;
            float cn = -0.1f * __logf(fmaxf(e, 1e-7f));
            local += cn * o;
        }
        __syncthreads();   // all E reads of this row done before flow overwrites
        float4 o0 = {fl[0], fl[1], fl[2], fl[3]};
        float4 o1 = {fl[4], fl[5], fl[6], fl[7]};
        float* frow = outbuf + (size_t)row * M_COLS + 8 * tid;
        *(float4*)frow = o0;
        *(float4*)(frow + 4) = o1;
    }

    __shared__ float red[256];
    red[tid] = local;
    __syncthreads();
    for (int s = 128; s > 0; s >>= 1) {
        if (tid < s) red[tid] += red[tid + s];
        __syncthreads();
    }
    if (tid == 0) atomicAdd(dist, red[0]);
}

// ---------------------------------------------------------------------------
extern "C" void kernel_launch(void* const* d_in, const int* in_sizes, int n_in,
                              void* d_out, int out_size, void* d_ws, size_t ws_size,
                              hipStream_t stream)
{
    const float* x     = (const float*)d_in[0];
    const float* y     = (const float*)d_in[1];
    const int*   iters = (const int*)d_in[2];
    const int*   ipe   = (const int*)d_in[3];
    float* out = (float*)d_out;
    float* ws  = (float*)d_ws;

    // ws layout (floats): ~2.26 MB total (within proven budget)
    float*        params = ws;                       // [0]=rho [1]=logb
    unsigned int* d2max  = (unsigned int*)(ws + 8);
    float* w  = ws + 16;                             // 8192
    float* u  = w + N_ROWS;                          // 2048
    float* mx = u + M_COLS;                          // 8192
    float* sx = mx + N_ROWS;                         // 8192
    float* x2 = sx + N_ROWS;                         // 8192
    float* my = x2 + N_ROWS;                         // 2048
    float* sy = my + M_COLS;                         // 2048
    float* y2 = sy + M_COLS;                         // 2048
    _Float16* gpart = (_Float16*)(y2 + M_COLS);      // 512*2048 fp16 = 2 MB

    float* cost = out;                               // cost -> E -> flow, in place
    float* dist = out + NM;

    hipMemsetAsync(d2max, 0, sizeof(unsigned int), stream);
    hipMemsetAsync(dist, 0, sizeof(float), stream);

    k_init<<<8, 256, 0, stream>>>(iters, ipe, params, u);
    rowstats<<<N_ROWS, 256, 0, stream>>>(x, mx, sx, x2);
    rowstats<<<M_COLS, 256, 0, stream>>>(y, my, sy, y2);
    gemm_cost_mfma<<<dim3(M_COLS / BN, N_ROWS / BM), 256, 0, stream>>>(
        x, y, mx, sx, x2, my, sy, y2, cost, d2max);

    sk_iter<true><<<SKB, 256, 0, stream>>>(out, u, w, gpart, params, d2max);
    sk_gred<<<M_COLS / 256, 256, 0, stream>>>(gpart, u);
    sk_iter<false><<<SKB, 256, 0, stream>>>(out, u, w, gpart, params, d2max);
    sk_gred<<<M_COLS / 256, 256, 0, stream>>>(gpart, u);
    sk_iter<false><<<SKB, 256, 0, stream>>>(out, u, w, gpart, params, d2max);
    sk_gred<<<M_COLS / 256, 256, 0, stream>>>(gpart, u);

    flow_dist<<<SKB, 256, 0, stream>>>(out, w, u, dist);
}

// Round 4
// 288.990 us; speedup vs baseline: 2.4789x; 1.3777x over previous
//
#include <hip/hip_runtime.h>
#include <math.h>

// Problem constants
#define N_ROWS 8192
#define M_COLS 2048
#define K_DIM  1024
#define NM     ((size_t)N_ROWS * M_COLS)

#define LAM       0.9090909090909091f         // GAMMA/(GAMMA+EPS)
#define LOG_M     7.624618986159398f          // log(2048)

#define SKB 512                                // sinkhorn blocks
#define RPB (N_ROWS / SKB)                     // 16 rows per block

typedef __bf16 bf16x8 __attribute__((ext_vector_type(8)));
typedef float  f32x4  __attribute__((ext_vector_type(4)));
typedef unsigned short u16x8 __attribute__((ext_vector_type(8)));
typedef _Float16 h8 __attribute__((ext_vector_type(8)));

// d_out memory map (64 MB):
//   row r (r<8192): bytes [r*8192, r*8192+4096)  = cost/E fp16 row r (2048 halves)
//                   bytes [r*8192+4096, r*8192+8192) = "hole"
//   Xb bf16 row i (16 MB): hole i>>1, slot i&1  -> byte (i>>1)*8192 + 4096 + (i&1)*2048
//   Yb bf16 row j ( 4 MB): hole 4096+(j>>1)     -> byte 32MB + (j>>1)*8192 + 4096 + (j&1)*2048
// GEMM writes cost into even chunks while reading Xb/Yb from odd chunks (disjoint).
// flow_dist finally overwrites everything with fp32 flow (block reads its own E rows
// into registers, one barrier, then stores).

static __device__ __forceinline__ size_t xb_off(int i) {
    return ((size_t)(i >> 1) << 13) + 4096 + ((size_t)(i & 1) << 11);
}
static __device__ __forceinline__ size_t yb_off(int j) {
    return ((size_t)1 << 25) + ((size_t)(j >> 1) << 13) + 4096 + ((size_t)(j & 1) << 11);
}

// ---------------------------------------------------------------------------
// init: params, u=1, d2max=0, dist=0
// ---------------------------------------------------------------------------
__global__ void k_init(const int* __restrict__ iters, const int* __restrict__ ipe,
                       float* __restrict__ params, float* __restrict__ u,
                       unsigned int* __restrict__ d2max, float* __restrict__ dist)
{
    const int t = blockIdx.x * 256 + threadIdx.x;
    if (t < M_COLS) u[t] = 1.0f;
    if (t == 0) {
        float ramp = 10.0f * (float)ipe[0];
        float rho;
        if (ramp == 0.0f) {
            rho = 1.1f;
        } else {
            float cur = fminf(fmaxf((float)iters[0], 0.0f), ramp);
            float phase = 1.0f - cur / ramp;
            rho = expf(-5.0f * phase * phase) + 0.1f;
        }
        rho = fminf(rho, 1.0f);
        params[0] = rho;
        params[1] = logf(rho) - LOG_M;   // logb = log(rho/M)
        *d2max = 0u;
        *dist = 0.0f;
    }
}

// ---------------------------------------------------------------------------
// fp32 pair -> packed bf16 (RNE)
// ---------------------------------------------------------------------------
static __device__ __forceinline__ unsigned pk_bf16(float a, float b) {
#if __has_builtin(__builtin_amdgcn_cvt_pk_bf16_f32)
    typedef __bf16 bf16x2 __attribute__((ext_vector_type(2)));
    bf16x2 r = __builtin_amdgcn_cvt_pk_bf16_f32(a, b);
    return __builtin_bit_cast(unsigned, r);
#else
    unsigned ua = __float_as_uint(a), ub = __float_as_uint(b);
    ua += 0x7FFFu + ((ua >> 16) & 1u);
    ub += 0x7FFFu + ((ub >> 16) & 1u);
    return (ua >> 16) | (ub & 0xFFFF0000u);
#endif
}

static __device__ __forceinline__ bf16x8 lds_frag(const unsigned short* p) {
    return __builtin_bit_cast(bf16x8, *(const u16x8*)p);
}

static __device__ __forceinline__ void gload16(const void* g, void* l) {
    __builtin_amdgcn_global_load_lds(
        (const __attribute__((address_space(1))) unsigned int*)g,
        (__attribute__((address_space(3))) unsigned int*)l, 16, 0, 0);
}

// ---------------------------------------------------------------------------
// per-row stats (min, sum, ||a-min||^2) + bf16 conversion into d_out holes.
// blocks 0..8191 = X rows; 8192..10239 = Y rows. 256 thr, 4 cols each.
// ---------------------------------------------------------------------------
__global__ __launch_bounds__(256) void rowstats_cvt(
    const float* __restrict__ X, const float* __restrict__ Y,
    unsigned char* __restrict__ outb,
    float* __restrict__ mx, float* __restrict__ sx, float* __restrict__ x2,
    float* __restrict__ my, float* __restrict__ sy, float* __restrict__ y2)
{
    const int b = blockIdx.x, tid = threadIdx.x;
    const bool isX = b < N_ROWS;
    const int row = isX ? b : b - N_ROWS;
    const float* src = isX ? (X + (size_t)row * K_DIM) : (Y + (size_t)row * K_DIM);
    const float4 v = ((const float4*)src)[tid];

    // bf16 convert into hole
    uint2 p; p.x = pk_bf16(v.x, v.y); p.y = pk_bf16(v.z, v.w);
    size_t off = isX ? xb_off(row) : yb_off(row);
    *(uint2*)(outb + off + (size_t)tid * 8) = p;

    float lmin = fminf(fminf(v.x, v.y), fminf(v.z, v.w));
    float lsum = v.x + v.y + v.z + v.w;
    float lsq  = v.x*v.x + v.y*v.y + v.z*v.z + v.w*v.w;

    __shared__ float rmin[256], rsum[256], rsq[256];
    rmin[tid] = lmin; rsum[tid] = lsum; rsq[tid] = lsq;
    __syncthreads();
    for (int s = 128; s > 0; s >>= 1) {
        if (tid < s) {
            rmin[tid] = fminf(rmin[tid], rmin[tid + s]);
            rsum[tid] += rsum[tid + s];
            rsq[tid]  += rsq[tid + s];
        }
        __syncthreads();
    }
    if (tid == 0) {
        float m = rmin[0], s = rsum[0], q = rsq[0];
        if (isX) { mx[row] = m; sx[row] = s; x2[row] = q - 2.f*m*s + (float)K_DIM*m*m; }
        else     { my[row] = m; sy[row] = s; y2[row] = q - 2.f*m*s + (float)K_DIM*m*m; }
    }
}

// ---------------------------------------------------------------------------
// m97-style MFMA GEMM on pre-converted bf16 + cost epilogue (fp16 store).
// 128x128 tile, 4 waves (2x2 of 64x64), BK=32, global_load_lds width 16.
// ---------------------------------------------------------------------------
__global__ __launch_bounds__(256) void gemm_cost_mfma(
    float* __restrict__ gbuf,
    const float* __restrict__ mx, const float* __restrict__ sx, const float* __restrict__ x2,
    const float* __restrict__ my, const float* __restrict__ sy, const float* __restrict__ y2,
    unsigned int* __restrict__ d2max)
{
    __shared__ unsigned short Ash[128 * 32];   // 8 KB, unpadded (global_load_lds)
    __shared__ unsigned short Bsh[128 * 32];   // 8 KB
    __shared__ float rmax[256];

    const unsigned char* outb = (const unsigned char*)gbuf;
    const int tid   = threadIdx.x;
    const int lane  = tid & 63;
    const int wave  = tid >> 6;
    const int wi    = wave >> 1;          // 0..1
    const int wj    = wave & 1;           // 0..1
    const int row16 = lane & 15;
    const int quad  = lane >> 4;          // 0..3
    const int i0 = blockIdx.y * 128, j0 = blockIdx.x * 128;

    // staging addresses: round p (0..1), wave w covers LDS rows (p*4+w)*16..+15
    const int chA = (lane & 3) * 16;       // byte chunk within 64 B row
    const unsigned char* pa[2];
    const unsigned char* pb[2];
    unsigned short* la[2];
    unsigned short* lb[2];
    #pragma unroll
    for (int p = 0; p < 2; ++p) {
        const int rt = (p * 4 + wave) * 16 + (lane >> 2);   // row in tile
        pa[p] = outb + xb_off(i0 + rt) + chA;
        pb[p] = outb + yb_off(j0 + rt) + chA;
        la[p] = &Ash[(p * 4 + wave) * 512];
        lb[p] = &Bsh[(p * 4 + wave) * 512];
    }

    f32x4 acc[4][4];
    #pragma unroll
    for (int u = 0; u < 4; ++u)
        #pragma unroll
        for (int v = 0; v < 4; ++v) acc[u][v] = (f32x4){0.f, 0.f, 0.f, 0.f};

    for (int kt = 0; kt < K_DIM; kt += 32) {
        gload16(pa[0], la[0]);
        gload16(pa[1], la[1]);
        gload16(pb[0], lb[0]);
        gload16(pb[1], lb[1]);
        pa[0] += 64; pa[1] += 64; pb[0] += 64; pb[1] += 64;
        __syncthreads();

        bf16x8 af[4], bf[4];
        #pragma unroll
        for (int t = 0; t < 4; ++t) {
            af[t] = lds_frag(&Ash[(wi * 64 + t * 16 + row16) * 32 + quad * 8]);
            bf[t] = lds_frag(&Bsh[(wj * 64 + t * 16 + row16) * 32 + quad * 8]);
        }
        #pragma unroll
        for (int ti = 0; ti < 4; ++ti)
            #pragma unroll
            for (int tj = 0; tj < 4; ++tj)
                acc[ti][tj] = __builtin_amdgcn_mfma_f32_16x16x32_bf16(
                    af[ti], bf[tj], acc[ti][tj], 0, 0, 0);
        __syncthreads();
    }

    // epilogue: C/D layout col=lane&15 (j), row=quad*4+reg (i); store fp16 cost
    _Float16* costh = (_Float16*)gbuf;
    float lmax = 0.0f;
    float myj[4], syj[4], yy[4];
    #pragma unroll
    for (int tj = 0; tj < 4; ++tj) {
        const int j = j0 + wj * 64 + tj * 16 + row16;
        myj[tj] = my[j]; syj[tj] = sy[j]; yy[tj] = y2[j];
    }
    #pragma unroll
    for (int ti = 0; ti < 4; ++ti) {
        #pragma unroll
        for (int reg = 0; reg < 4; ++reg) {
            const int i = i0 + wi * 64 + ti * 16 + quad * 4 + reg;
            const float mxi = mx[i], sxi = sx[i], xxi = x2[i];
            #pragma unroll
            for (int tj = 0; tj < 4; ++tj) {
                const int j = j0 + wj * 64 + tj * 16 + row16;
                float corr = mxi * syj[tj] + myj[tj] * sxi - (float)K_DIM * mxi * myj[tj];
                float d2 = xxi + yy[tj] - 2.0f * acc[ti][tj][reg] + 2.0f * corr;
                d2 = fmaxf(d2, 0.0f);
                lmax = fmaxf(lmax, d2);
                costh[(size_t)i * 4096 + j] = (_Float16)sqrtf(d2);
            }
        }
    }
    rmax[tid] = lmax;
    __syncthreads();
    for (int s = 128; s > 0; s >>= 1) {
        if (tid < s) rmax[tid] = fmaxf(rmax[tid], rmax[tid + s]);
        __syncthreads();
    }
    if (tid == 0) atomicMax(d2max, __float_as_uint(rmax[0]));
}

// ---------------------------------------------------------------------------
// Sinkhorn iteration on E = exp(-10*cn), matvec form.
//   t_r = sum_j E_rj u_j ; w_r = exp(-LAM*(logb + ln t_r))
//   gpart[b][j] = sum_{r in block} E_rj w_r     (fp16 partials)
// FIRST: converts fp16 cost -> fp16 E in place (elementwise, race-free).
// 512 blocks x 256 threads; block = 16 rows; thread = 8 contiguous cols.
// ---------------------------------------------------------------------------
template<bool FIRST>
__global__ __launch_bounds__(256) void sk_iter(
    float* __restrict__ outbuf, const float* __restrict__ u,
    float* __restrict__ w, _Float16* __restrict__ gpart,
    const float* __restrict__ params, const unsigned int* __restrict__ d2max)
{
    const int tid  = threadIdx.x;
    const int lane = tid & 63;
    const int wave = tid >> 6;
    const int r0   = blockIdx.x * RPB;
    const float logb = params[1];

    _Float16* Eb = (_Float16*)outbuf;
    h8 E[RPB];

    #pragma unroll
    for (int r = 0; r < RPB; ++r)
        E[r] = __builtin_bit_cast(h8, *(const uint4*)(Eb + (size_t)(r0 + r) * 4096 + 8 * tid));

    if (FIRST) {
        const float invC10 = 10.0f * rsqrtf(__uint_as_float(*d2max));
        #pragma unroll
        for (int r = 0; r < RPB; ++r) {
            h8 e;
            #pragma unroll
            for (int c = 0; c < 8; ++c)
                e[c] = (_Float16)__expf(-(float)E[r][c] * invC10);
            E[r] = e;
            *(uint4*)(Eb + (size_t)(r0 + r) * 4096 + 8 * tid) = __builtin_bit_cast(uint4, e);
        }
    }

    float4 ua = *(const float4*)(u + 8 * tid);
    float4 ub = *(const float4*)(u + 8 * tid + 4);
    float u8[8] = {ua.x, ua.y, ua.z, ua.w, ub.x, ub.y, ub.z, ub.w};

    // pass A: row sums t_r
    float pr[RPB];
    #pragma unroll
    for (int r = 0; r < RPB; ++r) {
        float s = 0.0f;
        #pragma unroll
        for (int c = 0; c < 8; ++c) s += (float)E[r][c] * u8[c];
        pr[r] = s;
    }
    #pragma unroll
    for (int r = 0; r < RPB; ++r)
        #pragma unroll
        for (int off = 32; off > 0; off >>= 1)
            pr[r] += __shfl_xor(pr[r], off, 64);

    __shared__ float R[RPB][4];
    __shared__ float W[RPB];
    if (lane == 0)
        #pragma unroll
        for (int r = 0; r < RPB; ++r) R[r][wave] = pr[r];
    __syncthreads();
    if (tid < RPB) {
        float t = R[tid][0] + R[tid][1] + R[tid][2] + R[tid][3];
        float wr = __expf(-LAM * (logb + __logf(t)));
        W[tid] = wr;
        w[r0 + tid] = wr;
    }
    __syncthreads();

    // pass B: column partials sum_r E*w
    float p[8] = {0.f, 0.f, 0.f, 0.f, 0.f, 0.f, 0.f, 0.f};
    #pragma unroll
    for (int r = 0; r < RPB; ++r) {
        const float wr = W[r];
        #pragma unroll
        for (int c = 0; c < 8; ++c) p[c] += (float)E[r][c] * wr;
    }
    h8 ph;
    #pragma unroll
    for (int c = 0; c < 8; ++c) ph[c] = (_Float16)p[c];
    *(uint4*)(gpart + (size_t)blockIdx.x * M_COLS + 8 * tid) = __builtin_bit_cast(uint4, ph);
}

// u_j = N / sigma_j,  sigma_j = sum_blocks gpart
__global__ __launch_bounds__(256) void sk_gred(
    const _Float16* __restrict__ gpart, float* __restrict__ u)
{
    const int col = blockIdx.x * 256 + threadIdx.x;
    float s = 0.0f;
    #pragma unroll 8
    for (int b = 0; b < SKB; ++b) s += (float)gpart[(size_t)b * M_COLS + col];
    u[col] = (float)N_ROWS / s;
}

// ---------------------------------------------------------------------------
// flow = E * w_r * u_j / (N*M)  (in-place: fp16 E rows -> fp32 flow rows)
// dist += sum cn * flow,  cn = -0.1*ln(E)
// All E rows loaded to registers, ONE barrier, then stores.
// ---------------------------------------------------------------------------
__global__ __launch_bounds__(256) void flow_dist(
    float* __restrict__ outbuf, const float* __restrict__ w,
    const float* __restrict__ u, float* __restrict__ dist)
{
    const int tid = threadIdx.x;
    const int r0  = blockIdx.x * RPB;
    const float invNM = 1.0f / ((float)N_ROWS * (float)M_COLS);
    _Float16* Eb = (_Float16*)outbuf;

    h8 E[RPB];
    #pragma unroll
    for (int r = 0; r < RPB; ++r)
        E[r] = __builtin_bit_cast(h8, *(const uint4*)(Eb + (size_t)(r0 + r) * 4096 + 8 * tid));

    __shared__ float W[RPB];
    if (tid < RPB) W[tid] = w[r0 + tid];

    float4 uA = *(const float4*)(u + 8 * tid);
    float4 uB = *(const float4*)(u + 8 * tid + 4);
    float u8[8] = {uA.x, uA.y, uA.z, uA.w, uB.x, uB.y, uB.z, uB.w};

    __syncthreads();   // drains all E loads + publishes W before any store

    float local = 0.0f;
    #pragma unroll
    for (int r = 0; r < RPB; ++r) {
        const float wr = W[r];
        float fl[8];
        #pragma unroll
        for (int c = 0; c < 8; ++c) {
            float e = (float)E[r][c];
            float o = e * wr * u8[c] * invNM;
            fl[c] = o;
            float cn = -0.1f * __logf(fmaxf(e, 1e-7f));
            local += cn * o;
        }
        float4 o0 = {fl[0], fl[1], fl[2], fl[3]};
        float4 o1 = {fl[4], fl[5], fl[6], fl[7]};
        float* frow = outbuf + (size_t)(r0 + r) * M_COLS + 8 * tid;
        *(float4*)frow = o0;
        *(float4*)(frow + 4) = o1;
    }

    __shared__ float red[256];
    red[tid] = local;
    __syncthreads();
    for (int s = 128; s > 0; s >>= 1) {
        if (tid < s) red[tid] += red[tid + s];
        __syncthreads();
    }
    if (tid == 0) atomicAdd(dist, red[0]);
}

// ---------------------------------------------------------------------------
extern "C" void kernel_launch(void* const* d_in, const int* in_sizes, int n_in,
                              void* d_out, int out_size, void* d_ws, size_t ws_size,
                              hipStream_t stream)
{
    const float* x     = (const float*)d_in[0];
    const float* y     = (const float*)d_in[1];
    const int*   iters = (const int*)d_in[2];
    const int*   ipe   = (const int*)d_in[3];
    float* out = (float*)d_out;
    float* ws  = (float*)d_ws;

    // ws layout (floats): ~4.3 MB total (proven budget)
    float*        params = ws;                       // [0]=rho [1]=logb
    unsigned int* d2max  = (unsigned int*)(ws + 8);
    float* w  = ws + 16;                             // 8192
    float* u  = w + N_ROWS;                          // 2048
    float* mx = u + M_COLS;                          // 8192
    float* sx = mx + N_ROWS;                         // 8192
    float* x2 = sx + N_ROWS;                         // 8192
    float* my = x2 + N_ROWS;                         // 2048
    float* sy = my + M_COLS;                         // 2048
    float* y2 = sy + M_COLS;                         // 2048
    _Float16* gpart = (_Float16*)(y2 + M_COLS);      // 512*2048 fp16 = 2 MB

    float* dist = out + NM;

    k_init<<<8, 256, 0, stream>>>(iters, ipe, params, u, d2max, dist);
    rowstats_cvt<<<N_ROWS + M_COLS, 256, 0, stream>>>(
        x, y, (unsigned char*)out, mx, sx, x2, my, sy, y2);
    gemm_cost_mfma<<<dim3(M_COLS / 128, N_ROWS / 128), 256, 0, stream>>>(
        out, mx, sx, x2, my, sy, y2, d2max);

    sk_iter<true><<<SKB, 256, 0, stream>>>(out, u, w, gpart, params, d2max);
    sk_gred<<<M_COLS / 256, 256, 0, stream>>>(gpart, u);
    sk_iter<false><<<SKB, 256, 0, stream>>>(out, u, w, gpart, params, d2max);
    sk_gred<<<M_COLS / 256, 256, 0, stream>>>(gpart, u);
    sk_iter<false><<<SKB, 256, 0, stream>>>(out, u, w, gpart, params, d2max);
    sk_gred<<<M_COLS / 256, 256, 0, stream>>>(gpart, u);

    flow_dist<<<SKB, 256, 0, stream>>>(out, w, u, dist);
}